// Round 5
// baseline (353.340 us; speedup 1.0000x reference)
//
#include <hip/hip_runtime.h>

typedef float vfloat4 __attribute__((ext_vector_type(4)));

__device__ __forceinline__ int iclamp(int v, int lo, int hi) {
  return v < lo ? lo : (v > hi ? hi : v);
}

// edge class: 0,1 = two left cells; 2 = interior; 3 = cell n-2; 4 = cell n-1
__device__ __forceinline__ int ecls(int g, int n) {
  return g < 2 ? g : (g >= n - 2 ? g - n + 5 : 2);
}

// ---------- 4x upscale weights (sample = 0.25*x - 0.375), Keys a=-0.5 ----------
// interior phases
#define W0_0 (-0.0439453125f)
#define W0_1 ( 0.3896484375f)
#define W0_2 ( 0.7275390625f)
#define W0_3 (-0.0732421875f)
#define W1_0 (-0.0068359375f)
#define W1_1 ( 0.0908203125f)
#define W1_2 ( 0.9638671875f)
#define W1_3 (-0.0478515625f)
// cell 0 (outputs 0..3), renormalized after dropping OOB taps; over patch v[2..4]
#define A0 ( 1.11194030f)   // 149/134
#define A1 (-0.11194030f)   // -15/134
#define B0 ( 1.05223881f)   // 987/938
#define B1 (-0.05223881f)   // -49/938
#define C0 ( 0.91985089f)   // 987/1073
#define C1 ( 0.08667288f)   // 93/1073
#define C2 (-0.00652377f)   // -7/1073
#define D0 ( 0.67788899f)   // 745/1099
#define D1 ( 0.36305732f)   // 399/1099
#define D2 (-0.04094632f)   // -45/1099
// cell 1 (outputs 4,5) over patch v[1..3]; outputs 6,7 are interior formulas
#define E0 ( 0.37324602f)   // 399/1069
#define E1 ( 0.69691301f)   // 745/1069
#define E2 (-0.07015903f)   // -75/1069
#define F0 ( 0.09020368f)   // 93/1031
#define F1 ( 0.95732299f)   // 987/1031
#define F2 (-0.04752667f)   // -49/1031

// ---------- 2x upscale weights (sample = 0.5*x - 0.25) ----------
#define U_0 (-0.0234375f)
#define U_1 ( 0.2265625f)
#define U_2 ( 0.8671875f)
#define U_3 (-0.0703125f)
// cell 0 phase 0 over v[2..3]; phase 1 over v[2..4]
#define Z0 ( 1.08823529f)   // 37/34
#define Z1 (-0.08823529f)   // -3/34
#define Y0 ( 0.81021898f)   // 111/137
#define Y1 ( 0.21167883f)   // 29/137
#define Y2 (-0.02189781f)   // -3/137
// cell 1 phase 0 over v[1..3]; phase 1 is interior-reverse
#define X0 ( 0.22137405f)   // 29/131
#define X1 ( 0.84732824f)   // 111/131
#define X2 (-0.06870229f)   // -9/131

// One 4-tap blend for 2x upscale, phase p in {0,1}, edge class cls.
// f0..f4 = 5 consecutive (edge-clamped) samples centered on the cell.
__device__ __forceinline__ float tap2(int cls, int p, float f0, float f1,
                                      float f2, float f3, float f4) {
  float r;
  if (cls == 2)      r = (p == 0) ? U_0*f0 + U_1*f1 + U_2*f2 + U_3*f3
                                  : U_3*f1 + U_2*f2 + U_1*f3 + U_0*f4;
  else if (cls == 0) r = (p == 0) ? Z0*f2 + Z1*f3
                                  : Y0*f2 + Y1*f3 + Y2*f4;
  else if (cls == 1) r = (p == 0) ? X0*f1 + X1*f2 + X2*f3
                                  : U_3*f1 + U_2*f2 + U_1*f3 + U_0*f4;
  else if (cls == 3) r = (p == 0) ? U_0*f0 + U_1*f1 + U_2*f2 + U_3*f3
                                  : X2*f1 + X1*f2 + X0*f3;
  else               r = (p == 0) ? Y2*f0 + Y1*f1 + Y0*f2
                                  : Z1*f1 + Z0*f2;
  return r;
}

// One 4-tap blend for 4x upscale, phase p in {0..3}, edge class cls.
__device__ __forceinline__ float tap4(int cls, int p, float f0, float f1,
                                      float f2, float f3, float f4) {
  float r;
  if (cls == 2)
    r = (p == 0) ? W0_0*f0 + W0_1*f1 + W0_2*f2 + W0_3*f3
      : (p == 1) ? W1_0*f0 + W1_1*f1 + W1_2*f2 + W1_3*f3
      : (p == 2) ? W1_3*f1 + W1_2*f2 + W1_1*f3 + W1_0*f4
                 : W0_3*f1 + W0_2*f2 + W0_1*f3 + W0_0*f4;
  else if (cls == 0)
    r = (p == 0) ? A0*f2 + A1*f3
      : (p == 1) ? B0*f2 + B1*f3
      : (p == 2) ? C0*f2 + C1*f3 + C2*f4
                 : D0*f2 + D1*f3 + D2*f4;
  else if (cls == 1)
    r = (p == 0) ? E0*f1 + E1*f2 + E2*f3
      : (p == 1) ? F0*f1 + F1*f2 + F2*f3
      : (p == 2) ? W1_3*f1 + W1_2*f2 + W1_1*f3 + W1_0*f4
                 : W0_3*f1 + W0_2*f2 + W0_1*f3 + W0_0*f4;
  else if (cls == 3)
    r = (p == 0) ? W0_0*f0 + W0_1*f1 + W0_2*f2 + W0_3*f3
      : (p == 1) ? W1_0*f0 + W1_1*f1 + W1_2*f2 + W1_3*f3
      : (p == 2) ? F2*f1 + F1*f2 + F0*f3
                 : E2*f1 + E1*f2 + E0*f3;
  else
    r = (p == 0) ? D2*f0 + D1*f1 + D0*f2
      : (p == 1) ? C2*f0 + C1*f1 + C0*f2
      : (p == 2) ? B1*f1 + B0*f2
                 : A1*f1 + A0*f2;
  return r;
}

// One block = one 16-row h256 slab of one image. Pyramid built in LDS,
// final 64x1024 output slab written with NT float4 stores (batch-flipped).
__global__ void __launch_bounds__(256, 4) fused_all(
    const float* __restrict__ cam256, const float* __restrict__ cam128,
    const float* __restrict__ cam64, const float* __restrict__ cam32,
    const float* __restrict__ w1, const float* __restrict__ b1,
    const float* __restrict__ w2, const float* __restrict__ b2,
    const float* __restrict__ w3, const float* __restrict__ b3,
    float* __restrict__ out) {
  __shared__ float s_h64[16 * 64];    //  4 KB
  __shared__ float s_h128[18 * 128];  //  9 KB
  __shared__ float s_h256[20 * 256];  // 20 KB

  const int tid = threadIdx.x;
  const int slab = blockIdx.x;  // 0..15
  const int b = blockIdx.y;     // 0..63
  const int s0 = slab * 16;     // h256 core rows [s0, s0+16)

  // Window row ranges (global coords), each covering the next level's halo.
  const int r_lo = s0 - 2 < 0 ? 0 : s0 - 2, r_hi = s0 + 17 > 255 ? 255 : s0 + 17;
  const int kr0 = r_lo >> 1, kr1 = r_hi >> 1;
  const int h256_row0 = 2 * kr0;                 // <=20 rows
  const int j_lo = kr0 - 2 < 0 ? 0 : kr0 - 2, j_hi = kr1 + 2 > 127 ? 127 : kr1 + 2;
  const int kj0 = j_lo >> 1, kj1 = j_hi >> 1;
  const int h128_row0 = 2 * kj0;                 // <=18 rows
  const int m_lo = kj0 - 2 < 0 ? 0 : kj0 - 2, m_hi = kj1 + 2 > 63 ? 63 : kj1 + 2;
  const int km0 = m_lo >> 1, km1 = m_hi >> 1;
  const int h64_row0 = 2 * km0;                  // <=16 rows

  const float w1_0 = w1[0], w1_1 = w1[1], b1_0 = b1[0];
  const float w2_0 = w2[0], w2_1 = w2[1], b2_0 = b2[0];
  const float w3_0 = w3[0], w3_1 = w3[1], b3_0 = b3[0];

  // ---- Phase A: h64 window from cam32 (global) + cam64 ----
  {
    const float* c32 = cam32 + (size_t)b * 32 * 32;
    const float* c64 = cam64 + (size_t)b * 64 * 64;
    const int nk = km1 - km0 + 1;
    for (int idx = tid; idx < nk * 32; idx += 256) {
      int k = km0 + (idx >> 5), g = idx & 31;
      int kcls = ecls(k, 32), gcls = ecls(g, 32);
      float f[5][5];
#pragma unroll
      for (int i = 0; i < 5; ++i) {
        int r = iclamp(k - 2 + i, 0, 31);
#pragma unroll
        for (int c = 0; c < 5; ++c) f[i][c] = c32[r * 32 + iclamp(g - 2 + c, 0, 31)];
      }
#pragma unroll
      for (int p = 0; p < 2; ++p) {
        float v[5];
#pragma unroll
        for (int c = 0; c < 5; ++c)
          v[c] = tap2(kcls, p, f[0][c], f[1][c], f[2][c], f[3][c], f[4][c]);
        float o0 = tap2(gcls, 0, v[0], v[1], v[2], v[3], v[4]);
        float o1 = tap2(gcls, 1, v[0], v[1], v[2], v[3], v[4]);
        int row = 2 * k + p;
        float2 cm = *(const float2*)(c64 + row * 64 + 2 * g);
        s_h64[(row - h64_row0) * 64 + 2 * g]     = fmaxf(w1_0 * o0 + w1_1 * cm.x + b1_0, 0.f);
        s_h64[(row - h64_row0) * 64 + 2 * g + 1] = fmaxf(w1_0 * o1 + w1_1 * cm.y + b1_0, 0.f);
      }
    }
  }
  __syncthreads();

  // ---- Phase B: h128 window from h64 (LDS) + cam128 ----
  {
    const float* c128 = cam128 + (size_t)b * 128 * 128;
    const int nk = kj1 - kj0 + 1;
    for (int idx = tid; idx < nk * 64; idx += 256) {
      int k = kj0 + (idx >> 6), g = idx & 63;
      int kcls = ecls(k, 64), gcls = ecls(g, 64);
      float f[5][5];
#pragma unroll
      for (int i = 0; i < 5; ++i) {
        int r = iclamp(k - 2 + i, 0, 63) - h64_row0;
#pragma unroll
        for (int c = 0; c < 5; ++c) f[i][c] = s_h64[r * 64 + iclamp(g - 2 + c, 0, 63)];
      }
#pragma unroll
      for (int p = 0; p < 2; ++p) {
        float v[5];
#pragma unroll
        for (int c = 0; c < 5; ++c)
          v[c] = tap2(kcls, p, f[0][c], f[1][c], f[2][c], f[3][c], f[4][c]);
        float o0 = tap2(gcls, 0, v[0], v[1], v[2], v[3], v[4]);
        float o1 = tap2(gcls, 1, v[0], v[1], v[2], v[3], v[4]);
        int row = 2 * k + p;
        float2 cm = *(const float2*)(c128 + row * 128 + 2 * g);
        s_h128[(row - h128_row0) * 128 + 2 * g]     = fmaxf(w2_0 * o0 + w2_1 * cm.x + b2_0, 0.f);
        s_h128[(row - h128_row0) * 128 + 2 * g + 1] = fmaxf(w2_0 * o1 + w2_1 * cm.y + b2_0, 0.f);
      }
    }
  }
  __syncthreads();

  // ---- Phase C: h256 window from h128 (LDS) + cam256 ----
  {
    const float* c256 = cam256 + (size_t)b * 256 * 256;
    const int nk = kr1 - kr0 + 1;
    for (int idx = tid; idx < nk * 128; idx += 256) {
      int k = kr0 + (idx >> 7), g = idx & 127;
      int kcls = ecls(k, 128), gcls = ecls(g, 128);
      float f[5][5];
#pragma unroll
      for (int i = 0; i < 5; ++i) {
        int r = iclamp(k - 2 + i, 0, 127) - h128_row0;
#pragma unroll
        for (int c = 0; c < 5; ++c) f[i][c] = s_h128[r * 128 + iclamp(g - 2 + c, 0, 127)];
      }
#pragma unroll
      for (int p = 0; p < 2; ++p) {
        float v[5];
#pragma unroll
        for (int c = 0; c < 5; ++c)
          v[c] = tap2(kcls, p, f[0][c], f[1][c], f[2][c], f[3][c], f[4][c]);
        float o0 = tap2(gcls, 0, v[0], v[1], v[2], v[3], v[4]);
        float o1 = tap2(gcls, 1, v[0], v[1], v[2], v[3], v[4]);
        int row = 2 * k + p;
        float2 cm = *(const float2*)(c256 + row * 256 + 2 * g);
        s_h256[(row - h256_row0) * 256 + 2 * g]     = fmaxf(w3_0 * o0 + w3_1 * cm.x + b3_0, 0.f);
        s_h256[(row - h256_row0) * 256 + 2 * g + 1] = fmaxf(w3_0 * o1 + w3_1 * cm.y + b3_0, 0.f);
      }
    }
  }
  __syncthreads();

  // ---- Phase D: final 4x upsample of the slab, batch-flipped output ----
  {
    float* outimg = out + (size_t)(63 - b) * 1024 * 1024;
    for (int idx = tid; idx < 16 * 256; idx += 256) {
      int k = s0 + (idx >> 8), g = idx & 255;
      int kcls = ecls(k, 256), gcls = ecls(g, 256);
      int rbase[5], cidx[5];
#pragma unroll
      for (int i = 0; i < 5; ++i) rbase[i] = (iclamp(k - 2 + i, 0, 255) - h256_row0) * 256;
#pragma unroll
      for (int c = 0; c < 5; ++c) cidx[c] = iclamp(g - 2 + c, 0, 255);
      float f[5][5];
#pragma unroll
      for (int i = 0; i < 5; ++i)
#pragma unroll
        for (int c = 0; c < 5; ++c) f[i][c] = s_h256[rbase[i] + cidx[c]];
#pragma unroll
      for (int p = 0; p < 4; ++p) {
        float v[5];
#pragma unroll
        for (int c = 0; c < 5; ++c)
          v[c] = tap4(kcls, p, f[0][c], f[1][c], f[2][c], f[3][c], f[4][c]);
        vfloat4 o;
        o.x = tap4(gcls, 0, v[0], v[1], v[2], v[3], v[4]);
        o.y = tap4(gcls, 1, v[0], v[1], v[2], v[3], v[4]);
        o.z = tap4(gcls, 2, v[0], v[1], v[2], v[3], v[4]);
        o.w = tap4(gcls, 3, v[0], v[1], v[2], v[3], v[4]);
        __builtin_nontemporal_store(
            o, (vfloat4*)(outimg + (size_t)(4 * k + p) * 1024 + 4 * g));
      }
    }
  }
}

extern "C" void kernel_launch(void* const* d_in, const int* in_sizes, int n_in_,
                              void* d_out, int out_size, void* d_ws, size_t ws_size,
                              hipStream_t stream) {
  const float* cam256 = (const float*)d_in[0];
  const float* cam128 = (const float*)d_in[1];
  const float* cam64  = (const float*)d_in[2];
  const float* cam32  = (const float*)d_in[3];
  const float* w1 = (const float*)d_in[4];
  const float* b1 = (const float*)d_in[5];
  const float* w2 = (const float*)d_in[6];
  const float* b2 = (const float*)d_in[7];
  const float* w3 = (const float*)d_in[8];
  const float* b3 = (const float*)d_in[9];
  float* out = (float*)d_out;

  fused_all<<<dim3(16, 64), 256, 0, stream>>>(cam256, cam128, cam64, cam32,
                                              w1, b1, w2, b2, w3, b3, out);
}